// Round 1
// baseline (34175.186 us; speedup 1.0000x reference)
//
#include <hip/hip_runtime.h>

// LSTM: B=8192, T=2048, D=1, H=256, C=10
// Persistent: 256 WGs x 512 threads (1/CU), 32 batch rows per WG.
// Per step: (32x256)@(256x1024) via v_mfma_f32_16x16x32_f16.
// R7 rewrite vs R6:
//  - Gate-major K-order; per-gate activation interleaved into the stream-gated
//    K-loop (trans/VALU hides in vmcnt stalls + 2-wave slip).
//  - A-frags (h) hoisted to 64 VGPRs at step top; both barriers sit at the
//    step top/bottom -> the entire K-loop+gates+write is barrier-free.
//  - Ring: 7 slots x 8 KB, sub-chunk = 1 B-frag (1 KB/wave, one gl_lds),
//    56 sub-chunks/step, distance-6 prefetch, uniform vmcnt(5) gate; chunk
//    stream wraps mod 56 across steps (weights step-invariant) so DMAs stay
//    in flight through the gates tail and the lgkm-only barriers.
//  - bias + W_x hoisted to 16 step-invariant regs (LDS regions removed).
//  - x prefetched 32 steps ahead via global_load_lds double-buffer (no more
//    per-32-step vmcnt(0) drain; all waves issue redundantly so every wave's
//    vmcnt accounting stays identical).
// kk=0 (64 KB) stays LDS-resident -> stream demand 448 KB/CU/step from L2.
// d_ws: 512 KB fp16 B-frags, byte off = kk*65536 + s*4096 + t*1024 + lane*16.

#define TT 2048
#define HH 256
#define CC 10

typedef _Float16 half8 __attribute__((ext_vector_type(8)));
typedef float float4v __attribute__((ext_vector_type(4)));

// LDS map (bytes)
#define WRES_OFF  0                      // kk=0 resident: 64 KB
#define RING_OFF  65536                  // 7 slots x 8192 = 57344
#define RING_SLOT 8192
#define HF_OFF    122880                 // h, A-frag order: 16 KB
#define XS_OFF    139264                 // x window double buffer: 2 x 4 KB
#define LDS_TOTAL 147456                 // 144 KB

__device__ __forceinline__ float frcp(float v)  { return __builtin_amdgcn_rcpf(v); }
__device__ __forceinline__ float fex2(float v)  { return __builtin_amdgcn_exp2f(v); }
__device__ __forceinline__ float fsig(float v)  { return frcp(1.0f + fex2(-1.442695040888963f * v)); }
__device__ __forceinline__ float ftanh(float v) { return 2.0f * frcp(1.0f + fex2(-2.885390081777927f * v)) - 1.0f; }

__device__ __forceinline__ void stream_issue(const void* g, void* l) {
    __builtin_amdgcn_global_load_lds((const __attribute__((address_space(1))) void*)g,
                                     (__attribute__((address_space(3))) void*)l, 16, 0, 0);
}
#define WAIT_VM5()     asm volatile("s_waitcnt vmcnt(5)" ::: "memory")
#define BARRIER_LGKM() asm volatile("s_waitcnt lgkmcnt(0)\n\ts_barrier" ::: "memory")

// Pack W_{g,i,f,o}h (fp32 [256][256], row k, col j) into fp16 MFMA B-frag order.
// unit u = ((kk*16+s)*4+t)*64 + lane ; elem j: k = kk*32 + (lane>>4)*8 + j,
// gate t, hidden col j_h = s*16 + (lane&15).
__global__ void pack_weights(const float* __restrict__ Wg, const float* __restrict__ Wi,
                             const float* __restrict__ Wf, const float* __restrict__ Wo,
                             _Float16* __restrict__ wsW) {
    int u = blockIdx.x * blockDim.x + threadIdx.x;   // 32768 units
    int kk = u >> 12, rem = u & 4095;
    int s = rem >> 8, rem2 = rem & 255;
    int t = rem2 >> 6, lane = rem2 & 63;
    int qq = lane >> 4, l15 = lane & 15;
    int jh = s * 16 + l15;
    const float* Wsrc = (t == 0) ? Wg : (t == 1) ? Wi : (t == 2) ? Wf : Wo;
    half8 v;
#pragma unroll
    for (int j = 0; j < 8; ++j) {
        int k = kk * 32 + qq * 8 + j;
        v[j] = (_Float16)Wsrc[k * HH + jh];
    }
    ((half8*)wsW)[u] = v;
}

__attribute__((amdgpu_waves_per_eu(2, 2)))
__global__ void __launch_bounds__(512) lstm_main(
    const float* __restrict__ x, const _Float16* __restrict__ wsW,
    const float* __restrict__ Wgx, const float* __restrict__ Wix,
    const float* __restrict__ Wfx, const float* __restrict__ Wox,
    const float* __restrict__ bg, const float* __restrict__ bi,
    const float* __restrict__ bfp, const float* __restrict__ bo,
    const float* __restrict__ Wp, const float* __restrict__ bp,
    float* __restrict__ out)
{
    extern __shared__ char smem[];
    _Float16* hf = (_Float16*)(smem + HF_OFF);

    const int tid  = threadIdx.x;
    const int wv   = tid >> 6;          // wave 0..7
    const int lane = tid & 63;
    const int q    = lane >> 4;
    const int l15  = lane & 15;
    const int s0   = wv * 2;            // this wave's first col-slice
    const int b0   = blockIdx.x * 32;

    // ---- prologue ----
    for (int i = tid; i < 8192; i += 512) hf[i] = (_Float16)0.f;    // h0 = 0
    {   // stage kk=0 into LDS (frag layout preserved)
        const uint4* src = (const uint4*)wsW;
        uint4* dst = (uint4*)(smem + WRES_OFF);
        for (int i = tid; i < 65536 / 16; i += 512) dst[i] = src[i];
    }
    {   // x window 0, synchronous
        float* xs0 = (float*)(smem + XS_OFF);
        const int row = tid >> 4, c2 = (tid & 15) * 2;
        float2 xv2 = *(const float2*)&x[(b0 + row) * TT + c2];
        *(float2*)&xs0[row * 32 + c2] = xv2;
    }
    // step-invariant per-lane bias & x-weight registers (col jj = (s0+sp)*16+l15)
    float bbr[4][2], wxr[4][2];
    {
        const float* bptr[4] = { bg, bi, bfp, bo };
        const float* wptr[4] = { Wgx, Wix, Wfx, Wox };
#pragma unroll
        for (int t = 0; t < 4; ++t)
#pragma unroll
            for (int sp = 0; sp < 2; ++sp) {
                const int jj = (s0 + sp) * 16 + l15;
                bbr[t][sp] = bptr[t][jj];
                wxr[t][sp] = wptr[t][jj];
            }
    }
    __syncthreads();   // full vmcnt/lgkm drain: ring vmcnt accounting starts at 0

    // per-lane / per-wave pointers
    const char* wl    = (const char*)wsW + s0 * 4096 + lane * 16;  // + kk*65536 + sp*4096 + t*1024
    char*       ringW = smem + RING_OFF + wv * 1024;               // wave-uniform; + slot*8192
    const char* ringR = smem + RING_OFF + wv * 1024 + lane * 16;
    const char* resB  = smem + WRES_OFF + s0 * 4096 + lane * 16;   // + sp*4096 + t*1024

    // prime sub-chunks 0..5 (gate 0): c -> kk=1+(c>>1), sp=c&1, slot=c
#pragma unroll
    for (int c = 0; c < 6; ++c)
        stream_issue(wl + (1 + (c >> 1)) * 65536 + (c & 1) * 4096,
                     ringW + c * RING_SLOT);

    float4v cst[2][2];
#pragma unroll
    for (int mt = 0; mt < 2; ++mt)
#pragma unroll
        for (int sp = 0; sp < 2; ++sp) cst[mt][sp] = (float4v){0.f, 0.f, 0.f, 0.f};

    // h-write scatter base (A-frag order): col j = 32wv+sp*16+l15, row mt*16+q*4+r
    const int wb = wv * 512 + ((l15 >> 3) * 16 + q * 4) * 8 + (l15 & 7);  // + mt*4096 + sp*256 + r*8

    // ---- time loop ----
#pragma unroll 1
    for (int ts = 0; ts < TT; ++ts) {
        // x window prefetch, 32 steps ahead (all waves redundantly, identical
        // bytes -> benign; keeps every wave's vmcnt queue composition equal)
        if ((ts & 31) == 0 && ts + 32 < TT) {
            const int w1 = (ts >> 5) + 1;
            char* xd = smem + XS_OFF + (w1 & 1) * 4096;
            const float* gx = x + (b0 + (lane >> 3)) * TT + (w1 << 5) + (lane & 7) * 4;
#pragma unroll
            for (int j = 0; j < 4; ++j)
                stream_issue(gx + j * 8 * TT, xd + j * 1024);
        }
        const float* xsL = (const float*)(smem + XS_OFF + ((ts >> 5) & 1) * 4096);

        // A-frags (h) hoisted to registers: 16 x ds_read_b128
        half8 a[8][2];
#pragma unroll
        for (int kk = 0; kk < 8; ++kk)
#pragma unroll
            for (int mt = 0; mt < 2; ++mt)
                a[kk][mt] = *(const half8*)(hf + mt * 4096 + kk * 512 + lane * 8);

        float xv[2][4];
#pragma unroll
        for (int mt = 0; mt < 2; ++mt)
#pragma unroll
            for (int r = 0; r < 4; ++r)
                xv[mt][r] = xsL[(mt * 16 + q * 4 + r) * 32 + (ts & 31)];

        BARRIER_LGKM();   // B1: all waves' h/x LDS reads retired; rest of step barrier-free

        float4v acc[2][2][4];
#pragma unroll
        for (int t = 0; t < 4; ++t) {
            // init: acc = bias + x_t * W_x (registers only)
#pragma unroll
            for (int sp = 0; sp < 2; ++sp)
#pragma unroll
                for (int mt = 0; mt < 2; ++mt)
#pragma unroll
                    for (int r = 0; r < 4; ++r)
                        acc[mt][sp][t][r] = bbr[t][sp] + xv[mt][r] * wxr[t][sp];
            // kk=0: resident in LDS
#pragma unroll
            for (int sp = 0; sp < 2; ++sp) {
                half8 bf = *(const half8*)(resB + sp * 4096 + t * 1024);
                acc[0][sp][t] = __builtin_amdgcn_mfma_f32_16x16x32_f16(a[0][0], bf, acc[0][sp][t], 0, 0, 0);
                acc[1][sp][t] = __builtin_amdgcn_mfma_f32_16x16x32_f16(a[0][1], bf, acc[1][sp][t], 0, 0, 0);
            }
            // kk=1..7 streamed: 14 sub-chunks for this gate, distance-6 prefetch
#pragma unroll
            for (int m = 0; m < 14; ++m) {
                const int c  = t * 14 + m;
                const int kk = 1 + (m >> 1), sp = m & 1;
                WAIT_VM5();                                    // sub-chunk c arrived
                half8 bf = *(const half8*)(ringR + (c % 7) * RING_SLOT);
                acc[0][sp][t] = __builtin_amdgcn_mfma_f32_16x16x32_f16(a[kk][0], bf, acc[0][sp][t], 0, 0, 0);
                acc[1][sp][t] = __builtin_amdgcn_mfma_f32_16x16x32_f16(a[kk][1], bf, acc[1][sp][t], 0, 0, 0);
                {   // issue sub-chunk c+6 (wraps into next step: weights step-invariant)
                    const int n  = (c + 6) % 56;
                    const int nm = n % 14, nt = n / 14;
                    stream_issue(wl + (1 + (nm >> 1)) * 65536 + (nm & 1) * 4096 + nt * 1024,
                                 ringW + (n % 7) * RING_SLOT);
                }
            }
            // this gate's activation, interleaved into the stream-gated region
#pragma unroll
            for (int sp = 0; sp < 2; ++sp)
#pragma unroll
                for (int mt = 0; mt < 2; ++mt)
#pragma unroll
                    for (int r = 0; r < 4; ++r)
                        acc[mt][sp][t][r] = (t == 0) ? ftanh(acc[mt][sp][t][r])
                                                     : fsig(acc[mt][sp][t][r]);
        }

        // state update + h write (lane owns rows mt*16+q*4+r, col (s0+sp)*16+l15)
#pragma unroll
        for (int mt = 0; mt < 2; ++mt)
#pragma unroll
            for (int sp = 0; sp < 2; ++sp)
#pragma unroll
                for (int r = 0; r < 4; ++r) {
                    float cn = acc[mt][sp][0][r] * acc[mt][sp][1][r]
                             + cst[mt][sp][r]   * acc[mt][sp][2][r];
                    cst[mt][sp][r] = cn;
                    hf[mt * 4096 + wb + sp * 256 + r * 8] =
                        (_Float16)(ftanh(cn) * acc[mt][sp][3][r]);
                }

        BARRIER_LGKM();   // B2: new h visible; ring DMAs stay in flight
    }

    // ---- epilogue: out = h_T @ W_ph + b_p ; wave wv handles rows 4wv..4wv+3 ----
#pragma unroll
    for (int rr = 0; rr < 4; ++rr) {
        int b = wv * 4 + rr;
        int mt = b >> 4, m = b & 15;
        float hv[4];
#pragma unroll
        for (int a2 = 0; a2 < 4; ++a2) {
            int j = lane + a2 * 64;
            int idx = mt * 4096 + (j >> 5) * 512 + (((j >> 3) & 3) * 16 + m) * 8 + (j & 7);
            hv[a2] = (float)hf[idx];
        }
#pragma unroll
        for (int c = 0; c < CC; ++c) {
            float sacc = 0.f;
#pragma unroll
            for (int a2 = 0; a2 < 4; ++a2) sacc += hv[a2] * Wp[(lane + a2 * 64) * CC + c];
#pragma unroll
            for (int off = 32; off > 0; off >>= 1) sacc += __shfl_xor(sacc, off, 64);
            if (lane == 0) out[(b0 + b) * CC + c] = sacc + bp[c];
        }
    }
}

extern "C" void kernel_launch(void* const* d_in, const int* in_sizes, int n_in,
                              void* d_out, int out_size, void* d_ws, size_t ws_size,
                              hipStream_t stream) {
    (void)in_sizes; (void)n_in; (void)out_size; (void)ws_size; // needs ws_size >= 524288
    const float* x   = (const float*)d_in[0];
    const float* Wgx = (const float*)d_in[1];
    const float* Wgh = (const float*)d_in[2];
    const float* Wix = (const float*)d_in[3];
    const float* Wih = (const float*)d_in[4];
    const float* Wfx = (const float*)d_in[5];
    const float* Wfh = (const float*)d_in[6];
    const float* Wox = (const float*)d_in[7];
    const float* Woh = (const float*)d_in[8];
    const float* Wp  = (const float*)d_in[9];
    const float* bg  = (const float*)d_in[10];
    const float* bi  = (const float*)d_in[11];
    const float* bf  = (const float*)d_in[12];
    const float* bo  = (const float*)d_in[13];
    const float* bp  = (const float*)d_in[14];
    _Float16* wsW = (_Float16*)d_ws;

    pack_weights<<<128, 256, 0, stream>>>(Wgh, Wih, Wfh, Woh, wsW);

    hipFuncSetAttribute((const void*)lstm_main,
                        hipFuncAttributeMaxDynamicSharedMemorySize, LDS_TOTAL);
    lstm_main<<<256, 512, LDS_TOTAL, stream>>>(
        x, wsW, Wgx, Wix, Wfx, Wox, bg, bi, bf, bo, Wp, bp, (float*)d_out);
}

// Round 2
// 12158.121 us; speedup vs baseline: 2.8109x; 2.8109x over previous
//
#include <hip/hip_runtime.h>

// LSTM: B=8192, T=2048, D=1, H=256, C=10
// Persistent: 256 WGs x 512 threads (1/CU), 32 batch rows per WG.
// Per step: (32x256)@(256x1024) via v_mfma_f32_16x16x32_f16.
// R8 = R6 structure (proven 12.3 ms) + gate-major stream order:
//  - Chunk m -> (t = m/7, kk = 1 + m%7): each gate's 7 streamed chunks are
//    contiguous, so gate t's activation bundle (tanh/sigmoid, ~128 trans ops)
//    runs right after its last chunk, INSIDE the stream-gated region, instead
//    of in a serial tail after all 28 chunks. Tail shrinks to update+write.
//  - A-frags re-read from LDS per chunk (2 x ds_read_b128 per iteration,
//    64/step vs R6's 16). NOT hoisted to registers: R7 proved the 64-VGPR
//    hoist pushes demand past the 128-reg allocation -> loop-invariant
//    scratch spills re-read every step = 46.7 GB HBM read (R1-R5 mode).
//  - Everything else identical to R6: no weights/bias in VGPRs, kk=0
//    LDS-resident, 4-slot x 16 KB ring, distance-3 prefetch, vmcnt(4) gate,
//    mod-28 wrap across steps, x staged to LDS every 32 steps (its vmcnt
//    drain is the only ring-drain, ~35 cyc/step amortized).
// d_ws: 512 KB fp16 B-frags, byte off = kk*65536 + s*4096 + t*1024 + lane*16.

#define TT 2048
#define HH 256
#define CC 10

typedef _Float16 half8 __attribute__((ext_vector_type(8)));
typedef float float4v __attribute__((ext_vector_type(4)));

// LDS map (bytes)
#define WRES_OFF  0                      // kk=0 resident: 64 KB
#define RING_OFF  65536                  // 4 slots x 16384
#define RING_SLOT 16384
#define HF_OFF    131072                 // h, A-frag order: 16 KB
#define BW_OFF    147456                 // bias[4][256] f32
#define WW_OFF    151552                 // w_x[4][256] f32
#define XS_OFF    155648                 // x[32 rows][32 steps] f32
#define LDS_TOTAL 159744

__device__ __forceinline__ float frcp(float v)  { return __builtin_amdgcn_rcpf(v); }
__device__ __forceinline__ float fex2(float v)  { return __builtin_amdgcn_exp2f(v); }
__device__ __forceinline__ float fsig(float v)  { return frcp(1.0f + fex2(-1.442695040888963f * v)); }
__device__ __forceinline__ float ftanh(float v) { return 2.0f * frcp(1.0f + fex2(-2.885390081777927f * v)) - 1.0f; }

__device__ __forceinline__ void stream_issue(const void* g, void* l) {
    __builtin_amdgcn_global_load_lds((const __attribute__((address_space(1))) void*)g,
                                     (__attribute__((address_space(3))) void*)l, 16, 0, 0);
}
#define WAIT_VM4()     asm volatile("s_waitcnt vmcnt(4)" ::: "memory")
#define BARRIER_LGKM() asm volatile("s_waitcnt lgkmcnt(0)\n\ts_barrier" ::: "memory")

// Pack W_{g,i,f,o}h (fp32 [256][256], row k, col j) into fp16 MFMA B-frag order.
// unit u = ((kk*16+s)*4+t)*64 + lane ; elem j: k = kk*32 + (lane>>4)*8 + j,
// gate t, hidden col j_h = s*16 + (lane&15).
__global__ void pack_weights(const float* __restrict__ Wg, const float* __restrict__ Wi,
                             const float* __restrict__ Wf, const float* __restrict__ Wo,
                             _Float16* __restrict__ wsW) {
    int u = blockIdx.x * blockDim.x + threadIdx.x;   // 32768 units
    int kk = u >> 12, rem = u & 4095;
    int s = rem >> 8, rem2 = rem & 255;
    int t = rem2 >> 6, lane = rem2 & 63;
    int q = lane >> 4, l15 = lane & 15;
    int jh = s * 16 + l15;
    const float* Wsrc = (t == 0) ? Wg : (t == 1) ? Wi : (t == 2) ? Wf : Wo;
    half8 v;
#pragma unroll
    for (int j = 0; j < 8; ++j) {
        int k = kk * 32 + q * 8 + j;
        v[j] = (_Float16)Wsrc[k * HH + jh];
    }
    ((half8*)wsW)[u] = v;
}

__attribute__((amdgpu_waves_per_eu(2, 2)))
__global__ void __launch_bounds__(512) lstm_main(
    const float* __restrict__ x, const _Float16* __restrict__ wsW,
    const float* __restrict__ Wgx, const float* __restrict__ Wix,
    const float* __restrict__ Wfx, const float* __restrict__ Wox,
    const float* __restrict__ bg, const float* __restrict__ bi,
    const float* __restrict__ bfp, const float* __restrict__ bo,
    const float* __restrict__ Wp, const float* __restrict__ bp,
    float* __restrict__ out)
{
    extern __shared__ char smem[];
    _Float16* hf  = (_Float16*)(smem + HF_OFF);
    float*    bwL = (float*)(smem + BW_OFF);
    float*    wwL = (float*)(smem + WW_OFF);
    float*    xsL = (float*)(smem + XS_OFF);

    const int tid  = threadIdx.x;
    const int wv   = tid >> 6;          // wave 0..7
    const int lane = tid & 63;
    const int q    = lane >> 4;
    const int l15  = lane & 15;
    const int s0   = wv * 2;            // this wave's first col-slice
    const int b0   = blockIdx.x * 32;

    // ---- prologue ----
    for (int i = tid; i < 8192; i += 512) hf[i] = (_Float16)0.f;    // h0 = 0
    {   // stage kk=0 into LDS (frag layout preserved)
        const uint4* src = (const uint4*)wsW;
        uint4* dst = (uint4*)(smem + WRES_OFF);
        for (int i = tid; i < 65536 / 16; i += 512) dst[i] = src[i];
    }
    {   // stage biases and x-weights
        const float* bptr[4] = { bg, bi, bfp, bo };
        const float* wptr[4] = { Wgx, Wix, Wfx, Wox };
        for (int i = tid; i < 1024; i += 512) {
            int t = i >> 8, j = i & 255;
            bwL[i] = bptr[t][j];
            wwL[i] = wptr[t][j];
        }
    }
    __syncthreads();   // full drain BEFORE priming the ring

    // per-lane / per-wave pointers
    const char* wl = (const char*)wsW + s0 * 4096 + lane * 16;  // + kk*65536 + sp*4096 + t*1024
    char* ringW = smem + RING_OFF + wv * 2048;                  // wave-uniform; + slot*16384 + sp*1024
    const _Float16* ringR = (const _Float16*)(smem + RING_OFF) + wv * 1024 + lane * 8;

    // prime ring: chunks m=0,1,2 -> (t=0, kk=1+m), slot = m
#pragma unroll
    for (int m = 0; m < 3; ++m) {
        const int kk = 1 + m, t = 0;
#pragma unroll
        for (int sp = 0; sp < 2; ++sp)
            stream_issue(wl + kk * 65536 + sp * 4096 + t * 1024,
                         ringW + m * RING_SLOT + sp * 1024);
    }

    float4v cst[2][2];
#pragma unroll
    for (int mt = 0; mt < 2; ++mt)
#pragma unroll
        for (int sp = 0; sp < 2; ++sp) cst[mt][sp] = (float4v){0.f, 0.f, 0.f, 0.f};

    // h-write scatter base (A-frag order): col j = 32wv+sp*16+l15, row mt*16+q*4+r
    const int wb = wv * 512 + ((l15 >> 3) * 16 + q * 4) * 8 + (l15 & 7);  // + mt*4096 + sp*256 + r*8

#define AREAD(kkv, mtv) (*(const half8*)(hf + (mtv) * 4096 + (kkv) * 512 + lane * 8))

    // ---- time loop ----
#pragma unroll 1
    for (int ts = 0; ts < TT; ++ts) {
        // x staging: once per 32 steps (the compiler's vmcnt drain here is the
        // only ring-drain; amortized ~35 cyc/step)
        if ((ts & 31) == 0) {
            const int row = tid >> 4;            // 0..31
            const int c2  = (tid & 15) * 2;      // 0,2,..,30
            float2 xv2 = *(const float2*)&x[(b0 + row) * TT + ts + c2];
            *(float2*)&xsL[row * 32 + c2] = xv2;
            BARRIER_LGKM();
        }

        float xv[2][4];
#pragma unroll
        for (int mt = 0; mt < 2; ++mt)
#pragma unroll
            for (int r = 0; r < 4; ++r)
                xv[mt][r] = xsL[(mt * 16 + q * 4 + r) * 32 + (ts & 31)];

        float4v acc[2][2][4];
        half8 a0, a1;

        // ---- gate-major: per gate t, init + kk=0 resident + 7 streamed
        //      chunks + this gate's activation (inside the stream-gated region)
#pragma unroll
        for (int t = 0; t < 4; ++t) {
            // acc init = bias + x_t * W_x (fp32, exact; operands from LDS)
#pragma unroll
            for (int sp = 0; sp < 2; ++sp) {
                const int jj = (s0 + sp) * 16 + l15;
                const float bb = bwL[t * 256 + jj];
                const float wx = wwL[t * 256 + jj];
#pragma unroll
                for (int mt = 0; mt < 2; ++mt)
#pragma unroll
                    for (int r = 0; r < 4; ++r)
                        acc[mt][sp][t][r] = bb + xv[mt][r] * wx;
            }
            // kk=0: resident in LDS
            a0 = AREAD(0, 0); a1 = AREAD(0, 1);
            {
                const char* lb = smem + WRES_OFF + s0 * 4096 + lane * 16;
#pragma unroll
                for (int sp = 0; sp < 2; ++sp) {
                    half8 bf = *(const half8*)(lb + sp * 4096 + t * 1024);
                    acc[0][sp][t] = __builtin_amdgcn_mfma_f32_16x16x32_f16(a0, bf, acc[0][sp][t], 0, 0, 0);
                    acc[1][sp][t] = __builtin_amdgcn_mfma_f32_16x16x32_f16(a1, bf, acc[1][sp][t], 0, 0, 0);
                }
            }
            // kk=1..7 streamed: 7 chunks for this gate, distance-3 prefetch
#pragma unroll
            for (int mm = 0; mm < 7; ++mm) {
                const int m = t * 7 + mm;          // global chunk index 0..27
                const int kk = 1 + mm, slot = m & 3;
                a0 = AREAD(kk, 0); a1 = AREAD(kk, 1);
                WAIT_VM4();                        // chunk m arrived
                half8 bf0 = *(const half8*)(ringR + slot * 8192);
                half8 bf1 = *(const half8*)(ringR + slot * 8192 + 512);
                acc[0][0][t] = __builtin_amdgcn_mfma_f32_16x16x32_f16(a0, bf0, acc[0][0][t], 0, 0, 0);
                acc[1][0][t] = __builtin_amdgcn_mfma_f32_16x16x32_f16(a1, bf0, acc[1][0][t], 0, 0, 0);
                acc[0][1][t] = __builtin_amdgcn_mfma_f32_16x16x32_f16(a0, bf1, acc[0][1][t], 0, 0, 0);
                acc[1][1][t] = __builtin_amdgcn_mfma_f32_16x16x32_f16(a1, bf1, acc[1][1][t], 0, 0, 0);
                {   // issue chunk m+3 (wraps into next step: weights step-invariant)
                    int n = m + 3; if (n >= 28) n -= 28;
                    const int tn = n / 7, kkn = 1 + (n % 7), sn = n & 3;
#pragma unroll
                    for (int sp = 0; sp < 2; ++sp)
                        stream_issue(wl + kkn * 65536 + sp * 4096 + tn * 1024,
                                     ringW + sn * RING_SLOT + sp * 1024);
                }
            }
            // this gate's activation, interleaved into the stream-gated region
#pragma unroll
            for (int sp = 0; sp < 2; ++sp)
#pragma unroll
                for (int mt = 0; mt < 2; ++mt)
#pragma unroll
                    for (int r = 0; r < 4; ++r)
                        acc[mt][sp][t][r] = (t == 0) ? ftanh(acc[mt][sp][t][r])
                                                     : fsig(acc[mt][sp][t][r]);
        }

        // state update (short tail: c/h update only; gates already activated)
        _Float16 hn[2][2][4];
#pragma unroll
        for (int mt = 0; mt < 2; ++mt)
#pragma unroll
            for (int sp = 0; sp < 2; ++sp)
#pragma unroll
                for (int r = 0; r < 4; ++r) {
                    float cn = acc[mt][sp][0][r] * acc[mt][sp][1][r]
                             + cst[mt][sp][r]   * acc[mt][sp][2][r];
                    cst[mt][sp][r] = cn;
                    hn[mt][sp][r] = (_Float16)(ftanh(cn) * acc[mt][sp][3][r]);
                }

        BARRIER_LGKM();   // B1: all waves' A/B LDS reads of this step retired
#pragma unroll
        for (int mt = 0; mt < 2; ++mt)
#pragma unroll
            for (int sp = 0; sp < 2; ++sp)
#pragma unroll
                for (int r = 0; r < 4; ++r)
                    hf[mt * 4096 + wb + sp * 256 + r * 8] = hn[mt][sp][r];
        BARRIER_LGKM();   // B2: new h visible; ring DMAs stay in flight
    }

    // ---- epilogue: out = h_T @ W_ph + b_p ; wave wv handles rows 4wv..4wv+3 ----
#pragma unroll
    for (int rr = 0; rr < 4; ++rr) {
        int b = wv * 4 + rr;
        int mt = b >> 4, m = b & 15;
        float hv[4];
#pragma unroll
        for (int a2 = 0; a2 < 4; ++a2) {
            int j = lane + a2 * 64;
            int idx = mt * 4096 + (j >> 5) * 512 + (((j >> 3) & 3) * 16 + m) * 8 + (j & 7);
            hv[a2] = (float)hf[idx];
        }
#pragma unroll
        for (int c = 0; c < CC; ++c) {
            float sacc = 0.f;
#pragma unroll
            for (int a2 = 0; a2 < 4; ++a2) sacc += hv[a2] * Wp[(lane + a2 * 64) * CC + c];
#pragma unroll
            for (int off = 32; off > 0; off >>= 1) sacc += __shfl_xor(sacc, off, 64);
            if (lane == 0) out[(b0 + b) * CC + c] = sacc + bp[c];
        }
    }
}

extern "C" void kernel_launch(void* const* d_in, const int* in_sizes, int n_in,
                              void* d_out, int out_size, void* d_ws, size_t ws_size,
                              hipStream_t stream) {
    (void)in_sizes; (void)n_in; (void)out_size; (void)ws_size; // needs ws_size >= 524288
    const float* x   = (const float*)d_in[0];
    const float* Wgx = (const float*)d_in[1];
    const float* Wgh = (const float*)d_in[2];
    const float* Wix = (const float*)d_in[3];
    const float* Wih = (const float*)d_in[4];
    const float* Wfx = (const float*)d_in[5];
    const float* Wfh = (const float*)d_in[6];
    const float* Wox = (const float*)d_in[7];
    const float* Woh = (const float*)d_in[8];
    const float* Wp  = (const float*)d_in[9];
    const float* bg  = (const float*)d_in[10];
    const float* bi  = (const float*)d_in[11];
    const float* bf  = (const float*)d_in[12];
    const float* bo  = (const float*)d_in[13];
    const float* bp  = (const float*)d_in[14];
    _Float16* wsW = (_Float16*)d_ws;

    pack_weights<<<128, 256, 0, stream>>>(Wgh, Wih, Wfh, Woh, wsW);

    hipFuncSetAttribute((const void*)lstm_main,
                        hipFuncAttributeMaxDynamicSharedMemorySize, LDS_TOTAL);
    lstm_main<<<256, 512, LDS_TOTAL, stream>>>(
        x, wsW, Wgx, Wix, Wfx, Wox, bg, bi, bf, bo, Wp, bp, (float*)d_out);
}

// Round 3
// 11661.846 us; speedup vs baseline: 2.9305x; 1.0426x over previous
//
#include <hip/hip_runtime.h>

// LSTM: B=8192, T=2048, D=1, H=256, C=10
// Persistent: 256 WGs x 512 threads (1/CU), 32 batch rows per WG.
// Per step: (32x256)@(256x1024) via v_mfma_f32_16x16x32_f16.
// R9: stream bypasses LDS (R8 post-mortem: LDS pipe was ~10-12k cyc of the
// 14.8k-cyc step -- the DMA ring wrote 448KB AND read 448KB through LDS).
//  - Streamed B-frags go global -> VGPR: 4-deep register ring sbuf[4][2]
//    (32 VGPRs, statically indexed, 24%4==0 so rotation is step-stable).
//    Compiler-tracked loads -> precise vmcnt waits; 64KB/CU in flight >>
//    BDP (~13.5KB/CU) keeps L2 saturated and bridges the tail/barriers.
//  - Freed ring LDS -> kk=0 AND kk=1 resident (128 KB): L2 stream drops
//    448 -> 384 KB/CU/step (floor 3.3 -> 2.84 us).
//  - kk-major chunk order (A-reads 16/wave, not R8's 64); gate t completes
//    at chunk m=20+t -> gates 0-2 activate inline inside the streamed
//    region, gate 3 + c/h update in the short tail.
//  - NO loop-invariant weight/bias hoists to regs (R7: demand >128 ->
//    loop-invariant scratch spills re-read every step = 46.7 GB HBM).
//    Diagnostic: hbm_bytes must stay ~36 MB.
// d_ws: 512 KB fp16 B-frags, byte off = kk*65536 + s*4096 + t*1024 + lane*16.

#define TT 2048
#define HH 256
#define CC 10

typedef _Float16 half8 __attribute__((ext_vector_type(8)));
typedef float float4v __attribute__((ext_vector_type(4)));

// LDS map (bytes)
#define WRES_OFF  0                      // kk=0,1 resident: 128 KB
#define HF_OFF    131072                 // h, A-frag order: 16 KB
#define BW_OFF    147456                 // bias[4][256] f32
#define WW_OFF    151552                 // w_x[4][256] f32
#define XS_OFF    155648                 // x[32 rows][32 steps] f32
#define LDS_TOTAL 159744

__device__ __forceinline__ float frcp(float v)  { return __builtin_amdgcn_rcpf(v); }
__device__ __forceinline__ float fex2(float v)  { return __builtin_amdgcn_exp2f(v); }
__device__ __forceinline__ float fsig(float v)  { return frcp(1.0f + fex2(-1.442695040888963f * v)); }
__device__ __forceinline__ float ftanh(float v) { return 2.0f * frcp(1.0f + fex2(-2.885390081777927f * v)) - 1.0f; }

#define BARRIER_LGKM() asm volatile("s_waitcnt lgkmcnt(0)\n\ts_barrier" ::: "memory")

// Pack W_{g,i,f,o}h (fp32 [256][256], row k, col j) into fp16 MFMA B-frag order.
// unit u = ((kk*16+s)*4+t)*64 + lane ; elem j: k = kk*32 + (lane>>4)*8 + j,
// gate t, hidden col j_h = s*16 + (lane&15).
__global__ void pack_weights(const float* __restrict__ Wg, const float* __restrict__ Wi,
                             const float* __restrict__ Wf, const float* __restrict__ Wo,
                             _Float16* __restrict__ wsW) {
    int u = blockIdx.x * blockDim.x + threadIdx.x;   // 32768 units
    int kk = u >> 12, rem = u & 4095;
    int s = rem >> 8, rem2 = rem & 255;
    int t = rem2 >> 6, lane = rem2 & 63;
    int q = lane >> 4, l15 = lane & 15;
    int jh = s * 16 + l15;
    const float* Wsrc = (t == 0) ? Wg : (t == 1) ? Wi : (t == 2) ? Wf : Wo;
    half8 v;
#pragma unroll
    for (int j = 0; j < 8; ++j) {
        int k = kk * 32 + q * 8 + j;
        v[j] = (_Float16)Wsrc[k * HH + jh];
    }
    ((half8*)wsW)[u] = v;
}

#define ACT_GATE(g)                                                            \
    _Pragma("unroll")                                                          \
    for (int sp_ = 0; sp_ < 2; ++sp_)                                          \
        _Pragma("unroll")                                                      \
        for (int mt_ = 0; mt_ < 2; ++mt_)                                      \
            _Pragma("unroll")                                                  \
            for (int r_ = 0; r_ < 4; ++r_)                                     \
                acc[mt_][sp_][g][r_] = ((g) == 0) ? ftanh(acc[mt_][sp_][g][r_])\
                                                  : fsig(acc[mt_][sp_][g][r_]);

__attribute__((amdgpu_waves_per_eu(2, 2)))
__global__ void __launch_bounds__(512) lstm_main(
    const float* __restrict__ x, const _Float16* __restrict__ wsW,
    const float* __restrict__ Wgx, const float* __restrict__ Wix,
    const float* __restrict__ Wfx, const float* __restrict__ Wox,
    const float* __restrict__ bg, const float* __restrict__ bi,
    const float* __restrict__ bfp, const float* __restrict__ bo,
    const float* __restrict__ Wp, const float* __restrict__ bp,
    float* __restrict__ out)
{
    extern __shared__ char smem[];
    _Float16* hf  = (_Float16*)(smem + HF_OFF);
    float*    bwL = (float*)(smem + BW_OFF);
    float*    wwL = (float*)(smem + WW_OFF);
    float*    xsL = (float*)(smem + XS_OFF);

    const int tid  = threadIdx.x;
    const int wv   = tid >> 6;          // wave 0..7
    const int lane = tid & 63;
    const int q    = lane >> 4;
    const int l15  = lane & 15;
    const int s0   = wv * 2;            // this wave's first col-slice
    const int b0   = blockIdx.x * 32;

    // ---- prologue ----
    for (int i = tid; i < 8192; i += 512) hf[i] = (_Float16)0.f;    // h0 = 0
    {   // stage kk=0,1 into LDS (frag layout preserved): 128 KB
        const uint4* src = (const uint4*)wsW;
        uint4* dst = (uint4*)(smem + WRES_OFF);
        for (int i = tid; i < 131072 / 16; i += 512) dst[i] = src[i];
    }
    {   // stage biases and x-weights
        const float* bptr[4] = { bg, bi, bfp, bo };
        const float* wptr[4] = { Wgx, Wix, Wfx, Wox };
        for (int i = tid; i < 1024; i += 512) {
            int t = i >> 8, j = i & 255;
            bwL[i] = bptr[t][j];
            wwL[i] = wptr[t][j];
        }
    }
    __syncthreads();

    // per-lane pointers
    const char* wl = (const char*)wsW + s0 * 4096 + lane * 16;      // + kk*65536 + sp*4096 + t*1024
    const char* lb = smem + WRES_OFF + s0 * 4096 + lane * 16;       // resident reads

    // prime register ring: chunks 0..3 = (kk=2, t=0..3)
    half8 sbuf[4][2];
#pragma unroll
    for (int m = 0; m < 4; ++m)
#pragma unroll
        for (int sp = 0; sp < 2; ++sp)
            sbuf[m][sp] = *(const half8*)(wl + 2 * 65536 + sp * 4096 + m * 1024);

    float4v cst[2][2];
#pragma unroll
    for (int mt = 0; mt < 2; ++mt)
#pragma unroll
        for (int sp = 0; sp < 2; ++sp) cst[mt][sp] = (float4v){0.f, 0.f, 0.f, 0.f};

    // h-write scatter base (A-frag order): col j = 32wv+sp*16+l15, row mt*16+q*4+r
    const int wb = wv * 512 + ((l15 >> 3) * 16 + q * 4) * 8 + (l15 & 7);  // + mt*4096 + sp*256 + r*8

#define AREAD(kkv, mtv) (*(const half8*)(hf + (mtv) * 4096 + (kkv) * 512 + lane * 8))

    // ---- time loop ----
#pragma unroll 1
    for (int ts = 0; ts < TT; ++ts) {
        // x staging: once per 32 steps (its compiler vmcnt wait briefly drains
        // the stream queue; amortized)
        if ((ts & 31) == 0) {
            const int row = tid >> 4;            // 0..31
            const int c2  = (tid & 15) * 2;      // 0,2,..,30
            float2 xv2 = *(const float2*)&x[(b0 + row) * TT + ts + c2];
            *(float2*)&xsL[row * 32 + c2] = xv2;
            BARRIER_LGKM();
        }

        float xv[2][4];
#pragma unroll
        for (int mt = 0; mt < 2; ++mt)
#pragma unroll
            for (int r = 0; r < 4; ++r)
                xv[mt][r] = xsL[(mt * 16 + q * 4 + r) * 32 + (ts & 31)];

        // acc init = bias + x_t * W_x (fp32, exact)
        float4v acc[2][2][4];
#pragma unroll
        for (int sp = 0; sp < 2; ++sp) {
            const int jj = (s0 + sp) * 16 + l15;
#pragma unroll
            for (int t = 0; t < 4; ++t) {
                const float bb = bwL[t * 256 + jj];
                const float wx = wwL[t * 256 + jj];
#pragma unroll
                for (int mt = 0; mt < 2; ++mt)
#pragma unroll
                    for (int r = 0; r < 4; ++r)
                        acc[mt][sp][t][r] = bb + xv[mt][r] * wx;
            }
        }

        half8 a0, a1;
        // kk=0,1: resident in LDS (gives the in-flight wrapped chunks slack)
#pragma unroll
        for (int kk = 0; kk < 2; ++kk) {
            a0 = AREAD(kk, 0); a1 = AREAD(kk, 1);
#pragma unroll
            for (int sp = 0; sp < 2; ++sp)
#pragma unroll
                for (int t = 0; t < 4; ++t) {
                    half8 bf = *(const half8*)(lb + kk * 65536 + sp * 4096 + t * 1024);
                    acc[0][sp][t] = __builtin_amdgcn_mfma_f32_16x16x32_f16(a0, bf, acc[0][sp][t], 0, 0, 0);
                    acc[1][sp][t] = __builtin_amdgcn_mfma_f32_16x16x32_f16(a1, bf, acc[1][sp][t], 0, 0, 0);
                }
        }

        // kk=2..7 streamed through the register ring, 24 chunks, distance-4
#pragma unroll
        for (int m = 0; m < 24; ++m) {
            const int kk = 2 + (m >> 2), t = m & 3, sl = m & 3;
            if (t == 0) { a0 = AREAD(kk, 0); a1 = AREAD(kk, 1); }
            const half8 bf0 = sbuf[sl][0];
            const half8 bf1 = sbuf[sl][1];
            acc[0][0][t] = __builtin_amdgcn_mfma_f32_16x16x32_f16(a0, bf0, acc[0][0][t], 0, 0, 0);
            acc[1][0][t] = __builtin_amdgcn_mfma_f32_16x16x32_f16(a1, bf0, acc[1][0][t], 0, 0, 0);
            acc[0][1][t] = __builtin_amdgcn_mfma_f32_16x16x32_f16(a0, bf1, acc[0][1][t], 0, 0, 0);
            acc[1][1][t] = __builtin_amdgcn_mfma_f32_16x16x32_f16(a1, bf1, acc[1][1][t], 0, 0, 0);
            {   // issue chunk m+4 (wraps into next step: weights step-invariant)
                const int n  = (m < 20) ? (m + 4) : (m - 20);
                const int nk = 2 + (n >> 2), nt = n & 3;
#pragma unroll
                for (int sp = 0; sp < 2; ++sp)
                    sbuf[sl][sp] = *(const half8*)(wl + nk * 65536 + sp * 4096 + nt * 1024);
            }
            // gate t fully accumulated at m=20+t: activate inside streamed region
            if (m == 20) { ACT_GATE(0) }
            if (m == 21) { ACT_GATE(1) }
            if (m == 22) { ACT_GATE(2) }
        }
        ACT_GATE(3)

        // state update (short tail: c/h update only; gates already activated)
        _Float16 hn[2][2][4];
#pragma unroll
        for (int mt = 0; mt < 2; ++mt)
#pragma unroll
            for (int sp = 0; sp < 2; ++sp)
#pragma unroll
                for (int r = 0; r < 4; ++r) {
                    float cn = acc[mt][sp][0][r] * acc[mt][sp][1][r]
                             + cst[mt][sp][r]   * acc[mt][sp][2][r];
                    cst[mt][sp][r] = cn;
                    hn[mt][sp][r] = (_Float16)(ftanh(cn) * acc[mt][sp][3][r]);
                }

        BARRIER_LGKM();   // B1: all waves' A/B LDS reads of this step retired
#pragma unroll
        for (int mt = 0; mt < 2; ++mt)
#pragma unroll
            for (int sp = 0; sp < 2; ++sp)
#pragma unroll
                for (int r = 0; r < 4; ++r)
                    hf[mt * 4096 + wb + sp * 256 + r * 8] = hn[mt][sp][r];
        BARRIER_LGKM();   // B2: new h visible; stream loads stay in flight
    }

    // ---- epilogue: out = h_T @ W_ph + b_p ; wave wv handles rows 4wv..4wv+3 ----
#pragma unroll
    for (int rr = 0; rr < 4; ++rr) {
        int b = wv * 4 + rr;
        int mt = b >> 4, m = b & 15;
        float hv[4];
#pragma unroll
        for (int a2 = 0; a2 < 4; ++a2) {
            int j = lane + a2 * 64;
            int idx = mt * 4096 + (j >> 5) * 512 + (((j >> 3) & 3) * 16 + m) * 8 + (j & 7);
            hv[a2] = (float)hf[idx];
        }
#pragma unroll
        for (int c = 0; c < CC; ++c) {
            float sacc = 0.f;
#pragma unroll
            for (int a2 = 0; a2 < 4; ++a2) sacc += hv[a2] * Wp[(lane + a2 * 64) * CC + c];
#pragma unroll
            for (int off = 32; off > 0; off >>= 1) sacc += __shfl_xor(sacc, off, 64);
            if (lane == 0) out[(b0 + b) * CC + c] = sacc + bp[c];
        }
    }
}

extern "C" void kernel_launch(void* const* d_in, const int* in_sizes, int n_in,
                              void* d_out, int out_size, void* d_ws, size_t ws_size,
                              hipStream_t stream) {
    (void)in_sizes; (void)n_in; (void)out_size; (void)ws_size; // needs ws_size >= 524288
    const float* x   = (const float*)d_in[0];
    const float* Wgx = (const float*)d_in[1];
    const float* Wgh = (const float*)d_in[2];
    const float* Wix = (const float*)d_in[3];
    const float* Wih = (const float*)d_in[4];
    const float* Wfx = (const float*)d_in[5];
    const float* Wfh = (const float*)d_in[6];
    const float* Wox = (const float*)d_in[7];
    const float* Woh = (const float*)d_in[8];
    const float* Wp  = (const float*)d_in[9];
    const float* bg  = (const float*)d_in[10];
    const float* bi  = (const float*)d_in[11];
    const float* bf  = (const float*)d_in[12];
    const float* bo  = (const float*)d_in[13];
    const float* bp  = (const float*)d_in[14];
    _Float16* wsW = (_Float16*)d_ws;

    pack_weights<<<128, 256, 0, stream>>>(Wgh, Wih, Wfh, Woh, wsW);

    hipFuncSetAttribute((const void*)lstm_main,
                        hipFuncAttributeMaxDynamicSharedMemorySize, LDS_TOTAL);
    lstm_main<<<256, 512, LDS_TOTAL, stream>>>(
        x, wsW, Wgx, Wix, Wfx, Wox, bg, bi, bf, bo, Wp, bp, (float*)d_out);
}